// Round 14
// baseline (1336.923 us; speedup 1.0000x reference)
//
#include <hip/hip_runtime.h>
#include <hip/hip_cooperative_groups.h>

namespace cg = cooperative_groups;

#define N_NODES 100000
#define N_EDGES 3200000
#define D 16

#define TILE 100                           // dst nodes per bucket
#define NB 1000                            // buckets == coop grid (4 blocks/CU needed)
#define CAP 3584                           // per-bucket ebuf region (mean 3200, +6.8 sigma)
#define T 512                              // coop threads per block
#define SEG (N_EDGES / NB)                 // 3200 edges per coop block segment
#define N4 (N_NODES * D / 4)               // 400000 float4 quarters

// fallback (round-11 proven) binning config
#define FNBLK 500
#define FSEG (N_EDGES / FNBLK)             // 6400
#define FBINT 1024
#define FCVTB 391                          // ceil(400000/1024)
#define LT 512

// ---- bf16 helpers (RNE) ----
__device__ __forceinline__ unsigned packbf(float a, float b) {
    unsigned ua = __float_as_uint(a); ua += 0x7FFFu + ((ua >> 16) & 1u);
    unsigned ub = __float_as_uint(b); ub += 0x7FFFu + ((ub >> 16) & 1u);
    return (ua >> 16) | (ub & 0xFFFF0000u);
}
#define BLO(u) __uint_as_float((u) << 16)
#define BHI(u) __uint_as_float((u) & 0xFFFF0000u)

// ---- shared aggregation + transform body (both paths) ----
// 4-lane group per node; 2 lanes/edge, 16B bf16 gathers; shuffles redistribute
// half-row sums into the quarter layout used by the 16x16 transform.
__device__ __forceinline__ void agg_xform(
    const float* __restrict__ self_f32, const unsigned* __restrict__ xbf,
    const unsigned* se2, const int* lofs, int n_loc,
    const float* sWl, const float* sWc, const float* sbc,
    float* __restrict__ xout, unsigned* __restrict__ xbf_out,
    int emit_bf, int b, int tid) {
    int q = tid & 3;
    int n = b * TILE + n_loc;                // NB*TILE == N_NODES, always valid

    float xv[4];
    if (self_f32) {
        float4 xq = *(const float4*)(self_f32 + (size_t)n * D + q * 4);
        xv[0] = xq.x; xv[1] = xq.y; xv[2] = xq.z; xv[3] = xq.w;
    } else {
        uint2 gx = *(const uint2*)(xbf + (size_t)n * 8 + q * 2);
        xv[0] = BLO(gx.x); xv[1] = BHI(gx.x); xv[2] = BLO(gx.y); xv[3] = BHI(gx.y);
    }

    int s0 = lofs[n_loc];
    int s1 = lofs[n_loc + 1];
    int deg = s1 - s0;
    int lane2 = q >> 1;
    int ho = (q & 1) * 4;

    float acc[8] = {0.f,0.f,0.f,0.f,0.f,0.f,0.f,0.f};
    int i = s0;
    for (; i + 8 <= s1; i += 8) {
        unsigned p0 = se2[i + 0 + lane2] & 0x1FFFF;
        unsigned p1 = se2[i + 2 + lane2] & 0x1FFFF;
        unsigned p2 = se2[i + 4 + lane2] & 0x1FFFF;
        unsigned p3 = se2[i + 6 + lane2] & 0x1FFFF;
        uint4 g0 = *(const uint4*)(xbf + (size_t)p0 * 8 + ho);
        uint4 g1 = *(const uint4*)(xbf + (size_t)p1 * 8 + ho);
        uint4 g2 = *(const uint4*)(xbf + (size_t)p2 * 8 + ho);
        uint4 g3 = *(const uint4*)(xbf + (size_t)p3 * 8 + ho);
        acc[0] += BLO(g0.x); acc[1] += BHI(g0.x); acc[2] += BLO(g0.y); acc[3] += BHI(g0.y);
        acc[4] += BLO(g0.z); acc[5] += BHI(g0.z); acc[6] += BLO(g0.w); acc[7] += BHI(g0.w);
        acc[0] += BLO(g1.x); acc[1] += BHI(g1.x); acc[2] += BLO(g1.y); acc[3] += BHI(g1.y);
        acc[4] += BLO(g1.z); acc[5] += BHI(g1.z); acc[6] += BLO(g1.w); acc[7] += BHI(g1.w);
        acc[0] += BLO(g2.x); acc[1] += BHI(g2.x); acc[2] += BLO(g2.y); acc[3] += BHI(g2.y);
        acc[4] += BLO(g2.z); acc[5] += BHI(g2.z); acc[6] += BLO(g2.w); acc[7] += BHI(g2.w);
        acc[0] += BLO(g3.x); acc[1] += BHI(g3.x); acc[2] += BLO(g3.y); acc[3] += BHI(g3.y);
        acc[4] += BLO(g3.z); acc[5] += BHI(g3.z); acc[6] += BLO(g3.w); acc[7] += BHI(g3.w);
    }
    for (; i + 2 <= s1; i += 2) {
        unsigned p = se2[i + lane2] & 0x1FFFF;
        uint4 g = *(const uint4*)(xbf + (size_t)p * 8 + ho);
        acc[0] += BLO(g.x); acc[1] += BHI(g.x); acc[2] += BLO(g.y); acc[3] += BHI(g.y);
        acc[4] += BLO(g.z); acc[5] += BHI(g.z); acc[6] += BLO(g.w); acc[7] += BHI(g.w);
    }
    if (i < s1 && lane2 == 0) {
        unsigned p = se2[i] & 0x1FFFF;
        uint4 g = *(const uint4*)(xbf + (size_t)p * 8 + ho);
        acc[0] += BLO(g.x); acc[1] += BHI(g.x); acc[2] += BLO(g.y); acc[3] += BHI(g.y);
        acc[4] += BLO(g.z); acc[5] += BHI(g.z); acc[6] += BLO(g.w); acc[7] += BHI(g.w);
    }
    #pragma unroll
    for (int k = 0; k < 8; k++) acc[k] += __shfl_xor(acc[k], 2, 4);

    int srcAbs = (tid & 63 & ~3) | (q >> 1);
    float inv = 1.0f / fmaxf((float)deg, 1.0f);
    float a[4];
    #pragma unroll
    for (int k = 0; k < 4; k++) {
        float lo = __shfl(acc[k], srcAbs);
        float hi = __shfl(acc[4 + k], srcAbs);
        a[k] = ((q & 1) ? hi : lo) * inv;
    }

    float o[4];
    #pragma unroll
    for (int j = 0; j < D; j++) {
        float p = 0.f;
        #pragma unroll
        for (int k = 0; k < 4; k++) {
            int kk = q * 4 + k;
            p += a[k] * sWl[j * D + kk] + xv[k] * sWc[j * D + kk];
        }
        p += __shfl_xor(p, 1, 4);
        p += __shfl_xor(p, 2, 4);
        if ((j >> 2) == q) o[j & 3] = p + sbc[j];
    }
    if (emit_bf) {
        uint2 ob; ob.x = packbf(o[0], o[1]); ob.y = packbf(o[2], o[3]);
        *(uint2*)(xbf_out + (size_t)n * 8 + q * 2) = ob;
    } else {
        *(float4*)(xout + (size_t)n * D + q * 4) = make_float4(o[0], o[1], o[2], o[3]);
    }
}

// ================== cooperative single-kernel path ==================
__global__ __launch_bounds__(T, 8) void fused_kernel(
        const float* __restrict__ x,
        const int* __restrict__ src, const int* __restrict__ dst,
        int* __restrict__ cursor, unsigned* __restrict__ ebuf,
        unsigned* __restrict__ xbf0, unsigned* __restrict__ xbf1,
        unsigned* __restrict__ xbf2,
        const float* __restrict__ Wl, const float* __restrict__ bl,
        const float* __restrict__ Wr, const float* __restrict__ Wlin,
        const float* __restrict__ blin, float* __restrict__ out) {
    cg::grid_group grid = cg::this_grid();

    // LDS pool ~25 KB -> LDS allows 6 blocks/CU (need 4)
    __shared__ __align__(16) char pool[25216];
    unsigned* se2  = (unsigned*)(pool);                  // 14336 persistent sorted edges (scatter reuses as staging)
    int*      lofs = (int*)(pool + 14336);               // 404 (pad to 416)
    int*      perm = (int*)(pool + 14752);               // 400 -> persistent ends 15152
    char* un = pool + 15152;                             // union region 10064 B
    // scatter view
    int*      lcnt   = (int*)(un);                       // 4000
    int*      ldiff  = (int*)(un + 4000);                // 4000
    unsigned short* lstart = (unsigned short*)(un + 8000); // 2004 -> 2008
    int*      wsum   = (int*)(un + 10016);               // 32
    // layer view
    int*   lcnt2 = (int*)(un);                           // 400
    int*   sdeg  = (int*)(un + 400);                     // 400
    float* sWl   = (float*)(un + 800);                   // 1024
    float* sWc   = (float*)(un + 1824);                  // 1024
    float* sbc   = (float*)(un + 2848);                  // 64

    int tid = threadIdx.x;
    int bid = blockIdx.x;
    int gid = bid * T + tid;

    // ======== phase A: cvt x->bf16 mirror + per-block dst histogram ========
    if (gid < N4) {
        float4 v = *(const float4*)(x + (size_t)gid * 4);
        uint2 o; o.x = packbf(v.x, v.y); o.y = packbf(v.z, v.w);
        *(uint2*)(xbf0 + (size_t)gid * 2) = o;
    }
    for (int i = tid; i < NB; i += T) lcnt[i] = 0;
    __syncthreads();
    int b0 = bid * SEG;
    for (int e = b0 + tid * 4; e < b0 + SEG; e += T * 4) {
        int4 d4 = *(const int4*)(dst + e);
        atomicAdd(&lcnt[(unsigned)d4.x / TILE], 1);
        atomicAdd(&lcnt[(unsigned)d4.y / TILE], 1);
        atomicAdd(&lcnt[(unsigned)d4.z / TILE], 1);
        atomicAdd(&lcnt[(unsigned)d4.w / TILE], 1);
    }
    __threadfence();
    grid.sync();

    // ======== phase B: reserve global space, LDS bucket-stage, coalesced write ========
    {
        int lane = tid & 63, wv = tid >> 6;
        int t2 = tid * 2;
        int c0 = (t2 < NB) ? lcnt[t2] : 0;
        int c1 = (t2 + 1 < NB) ? lcnt[t2 + 1] : 0;
        int v = c0 + c1, s = v;
        #pragma unroll
        for (int d_ = 1; d_ < 64; d_ <<= 1) {
            int u = __shfl_up(s, d_, 64);
            if (lane >= d_) s += u;
        }
        if (lane == 63) wsum[wv] = s;
        __syncthreads();
        if (tid == 0) {
            int a = 0;
            #pragma unroll
            for (int i = 0; i < 8; i++) { int t_ = wsum[i]; wsum[i] = a; a += t_; }
        }
        __syncthreads();
        int excl = wsum[wv] + s - v;
        if (t2 < NB) {
            lstart[t2] = (unsigned short)excl;
            int g0 = c0 ? (t2 * CAP + atomicAdd(&cursor[t2], c0)) : 0;
            ldiff[t2] = g0 - excl;
            lcnt[t2] = excl;
            int e1 = excl + c0;
            if (t2 + 1 < NB) {
                lstart[t2 + 1] = (unsigned short)e1;
                int g1 = c1 ? ((t2 + 1) * CAP + atomicAdd(&cursor[t2 + 1], c1)) : 0;
                ldiff[t2 + 1] = g1 - e1;
                lcnt[t2 + 1] = e1;
            }
        }
        if (tid == 0) lstart[NB] = (unsigned short)SEG;   // sentinel
    }
    __syncthreads();
    // stage edges bucket-sorted into se2 (reused as staging; rebuilt in phase C)
    for (int e = b0 + tid * 4; e < b0 + SEG; e += T * 4) {
        int4 d4 = *(const int4*)(dst + e);
        int4 s4 = *(const int4*)(src + e);
        unsigned b_; int pos;
        b_ = (unsigned)d4.x / TILE; pos = atomicAdd(&lcnt[b_], 1);
        se2[pos] = ((unsigned)(d4.x - b_ * TILE) << 17) | (unsigned)s4.x;
        b_ = (unsigned)d4.y / TILE; pos = atomicAdd(&lcnt[b_], 1);
        se2[pos] = ((unsigned)(d4.y - b_ * TILE) << 17) | (unsigned)s4.y;
        b_ = (unsigned)d4.z / TILE; pos = atomicAdd(&lcnt[b_], 1);
        se2[pos] = ((unsigned)(d4.z - b_ * TILE) << 17) | (unsigned)s4.z;
        b_ = (unsigned)d4.w / TILE; pos = atomicAdd(&lcnt[b_], 1);
        se2[pos] = ((unsigned)(d4.w - b_ * TILE) << 17) | (unsigned)s4.w;
    }
    __syncthreads();
    // coalesced write-out; bucket found by binary search (ties -> last index = non-empty bucket)
    for (int i = tid; i < SEG; i += T) {
        int lo = 0, hi = NB;
        while (hi - lo > 1) {
            int mid = (lo + hi) >> 1;
            if ((int)lstart[mid] <= i) lo = mid; else hi = mid;
        }
        ebuf[ldiff[lo] + i] = se2[i];
    }
    __threadfence();
    grid.sync();

    // ======== phase C: per-bucket counting sort (ebuf read twice) + rank + layer 0 ========
    int b = bid;
    int base = b * CAP;
    int nE = min(cursor[b], CAP);

    if (tid < TILE) lcnt2[tid] = 0;
    __syncthreads();
    for (int i = tid; i < nE; i += T)
        atomicAdd(&lcnt2[ebuf[base + i] >> 17], 1);
    __syncthreads();
    if (tid < 64) {                          // single-wave scan, 2 counters/lane
        int l2 = tid * 2;
        int c0 = (l2 < TILE) ? lcnt2[l2] : 0;
        int c1 = (l2 + 1 < TILE) ? lcnt2[l2 + 1] : 0;
        int v = c0 + c1, s = v;
        #pragma unroll
        for (int d_ = 1; d_ < 64; d_ <<= 1) {
            int u = __shfl_up(s, d_, 64);
            if (tid >= d_) s += u;
        }
        int excl = s - v;
        if (l2 < TILE) {
            lofs[l2] = excl; sdeg[l2] = c0; lcnt2[l2] = excl;
            int e1 = excl + c0;
            if (l2 + 1 < TILE) { lofs[l2 + 1] = e1; sdeg[l2 + 1] = c1; lcnt2[l2 + 1] = e1; }
        }
        if (tid == 63) lofs[TILE] = s;       // == nE
    }
    if (tid >= 64 && tid < 320) {            // concurrent layer-0 weight load
        int k = tid - 64;
        sWl[k] = Wl[k];
        sWc[k] = Wr[k] + Wlin[k];
    }
    if (tid >= 320 && tid < 336) {
        int k = tid - 320;
        sbc[k] = bl[k] + blin[k];
    }
    __syncthreads();
    if (tid < TILE) {                        // degree rank (desc)
        int dm = sdeg[tid];
        int r = 0;
        for (int j = 0; j < TILE; j++) {
            int dj = sdeg[j];
            r += (dj > dm) || (dj == dm && j < tid);
        }
        perm[r] = tid;
    }
    for (int i = tid; i < nE; i += T) {      // reorder into LDS-resident sorted list
        unsigned p = ebuf[base + i];
        int pos = atomicAdd(&lcnt2[p >> 17], 1);
        se2[pos] = p;
    }
    __syncthreads();

    int grp = tid >> 2;
    if (grp < TILE)
        agg_xform(x, xbf0, se2, lofs, perm[grp], sWl, sWc, sbc,
                  nullptr, xbf1, 1, b, tid);
    __threadfence();
    grid.sync();

    // ======== phase D: layer 1 ========
    if (tid < 256) {
        sWl[tid] = Wl[256 + tid];
        sWc[tid] = Wr[256 + tid] + Wlin[256 + tid];
    }
    if (tid < 16) sbc[tid] = bl[16 + tid] + blin[16 + tid];
    __syncthreads();
    if (grp < TILE)
        agg_xform(nullptr, xbf1, se2, lofs, perm[grp], sWl, sWc, sbc,
                  nullptr, xbf2, 1, b, tid);
    __threadfence();
    grid.sync();

    // ======== phase E: layer 2 -> fp32 out ========
    if (tid < 256) {
        sWl[tid] = Wl[512 + tid];
        sWc[tid] = Wr[512 + tid] + Wlin[512 + tid];
    }
    if (tid < 16) sbc[tid] = bl[32 + tid] + blin[32 + tid];
    __syncthreads();
    if (grp < TILE)
        agg_xform(nullptr, xbf2, se2, lofs, perm[grp], sWl, sWc, sbc,
                  out, nullptr, 0, b, tid);
}

// ================== fallback multi-dispatch path (round-11 proven) ==================
__global__ __launch_bounds__(FBINT) void fb_pre_kernel(
        const float* __restrict__ x, unsigned* __restrict__ xbf,
        const int* __restrict__ src, const int* __restrict__ dst,
        int* __restrict__ cursor, unsigned* __restrict__ ebuf, int E, int n4) {
    __shared__ int lcnt[NB];
    __shared__ int ldiff[NB];
    __shared__ unsigned sorted[FSEG];
    __shared__ unsigned short sbkt[FSEG];
    int tid = threadIdx.x;

    if (blockIdx.x >= FNBLK) {             // cvt path
        int t = (blockIdx.x - FNBLK) * FBINT + tid;
        if (t < n4) {
            float4 v = *(const float4*)(x + (size_t)t * 4);
            uint2 o; o.x = packbf(v.x, v.y); o.y = packbf(v.z, v.w);
            *(uint2*)(xbf + (size_t)t * 2) = o;
        }
        return;
    }

    for (int i = tid; i < NB; i += FBINT) lcnt[i] = 0;
    __syncthreads();
    int b0 = blockIdx.x * FSEG, b1 = min(E, b0 + FSEG);
    for (int e = b0 + tid * 4; e < b1; e += FBINT * 4) {
        int4 d4 = *(const int4*)(dst + e);
        atomicAdd(&lcnt[(unsigned)d4.x / TILE], 1);
        atomicAdd(&lcnt[(unsigned)d4.y / TILE], 1);
        atomicAdd(&lcnt[(unsigned)d4.z / TILE], 1);
        atomicAdd(&lcnt[(unsigned)d4.w / TILE], 1);
    }
    __syncthreads();
    {
        int v = (tid < NB) ? lcnt[tid] : 0;
        sorted[tid] = (unsigned)v;
        __syncthreads();
        for (int off = 1; off < FBINT; off <<= 1) {
            unsigned t = (tid >= off) ? sorted[tid - off] : 0u;
            __syncthreads();
            sorted[tid] += t;
            __syncthreads();
        }
        if (tid < NB) {
            int excl = (int)sorted[tid] - v;
            int g = v ? (tid * CAP + atomicAdd(&cursor[tid], v)) : 0;
            ldiff[tid] = g - excl;
            lcnt[tid] = excl;
        }
        __syncthreads();
    }
    for (int e = b0 + tid * 4; e < b1; e += FBINT * 4) {
        int4 d4 = *(const int4*)(dst + e);
        int4 s4 = *(const int4*)(src + e);
        unsigned b_; int pos;
        b_ = (unsigned)d4.x / TILE; pos = atomicAdd(&lcnt[b_], 1);
        sorted[pos] = ((unsigned)(d4.x - b_ * TILE) << 17) | (unsigned)s4.x; sbkt[pos] = (unsigned short)b_;
        b_ = (unsigned)d4.y / TILE; pos = atomicAdd(&lcnt[b_], 1);
        sorted[pos] = ((unsigned)(d4.y - b_ * TILE) << 17) | (unsigned)s4.y; sbkt[pos] = (unsigned short)b_;
        b_ = (unsigned)d4.z / TILE; pos = atomicAdd(&lcnt[b_], 1);
        sorted[pos] = ((unsigned)(d4.z - b_ * TILE) << 17) | (unsigned)s4.z; sbkt[pos] = (unsigned short)b_;
        b_ = (unsigned)d4.w / TILE; pos = atomicAdd(&lcnt[b_], 1);
        sorted[pos] = ((unsigned)(d4.w - b_ * TILE) << 17) | (unsigned)s4.w; sbkt[pos] = (unsigned short)b_;
    }
    __syncthreads();
    int nLoc = b1 - b0;
    for (int i = tid; i < nLoc; i += FBINT) {
        int b_ = sbkt[i];
        ebuf[ldiff[b_] + i] = sorted[i];
    }
}

__global__ __launch_bounds__(LT) void fb_layer0(
        const float* __restrict__ xin, const unsigned* __restrict__ xbf,
        unsigned* __restrict__ ebuf, const int* __restrict__ cnt,
        int* __restrict__ node_start, int* __restrict__ gperm,
        const float* __restrict__ Wl, const float* __restrict__ bl,
        const float* __restrict__ Wr, const float* __restrict__ Wlin,
        const float* __restrict__ blin,
        unsigned* __restrict__ xbf_out) {
    __shared__ unsigned se[CAP];
    __shared__ unsigned se2[CAP];
    __shared__ int lcnt[TILE];
    __shared__ int lofs[TILE + 1];
    __shared__ int sdeg[TILE];
    __shared__ int perm[TILE];
    __shared__ float sWl[D * D];
    __shared__ float sWc[D * D];
    __shared__ float sbc[D];

    int tid = threadIdx.x;
    int b = blockIdx.x;
    int base = b * CAP;
    int nE = min(cnt[b], CAP);

    if (tid < D * D) { sWl[tid] = Wl[tid]; sWc[tid] = Wr[tid] + Wlin[tid]; }
    if (tid < D) sbc[tid] = bl[tid] + blin[tid];
    if (tid < TILE) lcnt[tid] = 0;
    __syncthreads();
    for (int i = tid; i < nE; i += LT) {
        unsigned p = ebuf[base + i];
        se[i] = p;
        atomicAdd(&lcnt[p >> 17], 1);
    }
    __syncthreads();
    if (tid < 64) {
        int l2 = tid * 2;
        int c0 = (l2 < TILE) ? lcnt[l2] : 0;
        int c1 = (l2 + 1 < TILE) ? lcnt[l2 + 1] : 0;
        int v = c0 + c1, s = v;
        #pragma unroll
        for (int d_ = 1; d_ < 64; d_ <<= 1) {
            int u = __shfl_up(s, d_, 64);
            if (tid >= d_) s += u;
        }
        int excl = s - v;
        if (l2 < TILE) {
            lofs[l2] = excl; sdeg[l2] = c0; lcnt[l2] = excl;
            node_start[b * TILE + l2] = excl;
            int e1 = excl + c0;
            if (l2 + 1 < TILE) {
                lofs[l2 + 1] = e1; sdeg[l2 + 1] = c1; lcnt[l2 + 1] = e1;
                node_start[b * TILE + l2 + 1] = e1;
            }
        }
        if (tid == 63) lofs[TILE] = s;
    }
    __syncthreads();
    if (tid < TILE) {
        int dm = sdeg[tid];
        int r = 0;
        for (int j = 0; j < TILE; j++) {
            int dj = sdeg[j];
            r += (dj > dm) || (dj == dm && j < tid);
        }
        perm[r] = tid;
        gperm[b * TILE + r] = tid;
    }
    for (int i = tid; i < nE; i += LT) {
        unsigned p = se[i];
        int pos = atomicAdd(&lcnt[p >> 17], 1);
        se2[pos] = p;
    }
    __syncthreads();
    for (int i = tid; i < nE; i += LT)
        ebuf[base + i] = se2[i];

    int grp = tid >> 2;
    if (grp >= TILE) return;
    agg_xform(xin, xbf, se2, lofs, perm[grp], sWl, sWc, sbc,
              nullptr, xbf_out, 1, b, tid);
}

__global__ __launch_bounds__(LT) void fb_layerN(
        const unsigned* __restrict__ xbf,
        const unsigned* __restrict__ ebuf, const int* __restrict__ cnt,
        const int* __restrict__ node_start, const int* __restrict__ gperm,
        const float* __restrict__ Wl, const float* __restrict__ bl,
        const float* __restrict__ Wr, const float* __restrict__ Wlin,
        const float* __restrict__ blin,
        float* __restrict__ xout, unsigned* __restrict__ xbf_out,
        int emit_bf) {
    __shared__ unsigned se2[CAP];
    __shared__ int lofs[TILE + 1];
    __shared__ float sWl[D * D];
    __shared__ float sWc[D * D];
    __shared__ float sbc[D];

    int tid = threadIdx.x;
    int b = blockIdx.x;
    int base = b * CAP;
    int nE = min(cnt[b], CAP);

    if (tid < D * D) { sWl[tid] = Wl[tid]; sWc[tid] = Wr[tid] + Wlin[tid]; }
    if (tid < D) sbc[tid] = bl[tid] + blin[tid];
    if (tid < TILE) lofs[tid] = node_start[b * TILE + tid];
    if (tid == 0) lofs[TILE] = nE;
    for (int i = tid; i < nE; i += LT) se2[i] = ebuf[base + i];
    int grp = tid >> 2;
    int n_loc = (grp < TILE) ? gperm[b * TILE + grp] : 0;
    __syncthreads();

    if (grp >= TILE) return;
    agg_xform(nullptr, xbf, se2, lofs, n_loc, sWl, sWc, sbc,
              xout, xbf_out, emit_bf, b, tid);
}

extern "C" void kernel_launch(void* const* d_in, const int* in_sizes, int n_in,
                              void* d_out, int out_size, void* d_ws, size_t ws_size,
                              hipStream_t stream) {
    const float* x    = (const float*)d_in[0];
    const int*   ei   = (const int*)d_in[1];   // (2, E): first E = src, next E = dst
    const float* Wl   = (const float*)d_in[2];
    const float* bl   = (const float*)d_in[3];
    const float* Wr   = (const float*)d_in[4];
    const float* Wlin = (const float*)d_in[5];
    const float* blin = (const float*)d_in[6];
    float* out = (float*)d_out;

    const int* src = ei;
    const int* dst = ei + N_EDGES;

    char* w = (char*)d_ws;
    unsigned* ebuf = (unsigned*)w;  w += (size_t)NB * CAP * 4;        // 14.3 MB
    unsigned* xbf0 = (unsigned*)w;  w += (size_t)N_NODES * 8 * 4;     // 3.2 MB
    unsigned* xbf1 = (unsigned*)w;  w += (size_t)N_NODES * 8 * 4;     // 3.2 MB
    unsigned* xbf2 = (unsigned*)w;  w += (size_t)N_NODES * 8 * 4;     // 3.2 MB
    int* cursor     = (int*)w;      w += (size_t)NB * 4;
    int* node_start = (int*)w;      w += (size_t)NB * TILE * 4;       // 400 KB (fallback)
    int* gperm      = (int*)w;      w += (size_t)NB * TILE * 4;       // 400 KB (fallback)

    hipMemsetAsync(cursor, 0, (size_t)NB * 4, stream);

    void* args[] = {
        (void*)&x, (void*)&src, (void*)&dst, (void*)&cursor, (void*)&ebuf,
        (void*)&xbf0, (void*)&xbf1, (void*)&xbf2,
        (void*)&Wl, (void*)&bl, (void*)&Wr, (void*)&Wlin, (void*)&blin, (void*)&out
    };
    hipError_t err = hipLaunchCooperativeKernel((void*)fused_kernel, dim3(NB), dim3(T),
                                                args, 0, stream);
    if (err != hipSuccess) {
        // fallback: proven multi-dispatch pipeline
        fb_pre_kernel<<<FNBLK + FCVTB, FBINT, 0, stream>>>(
            x, xbf0, src, dst, cursor, ebuf, N_EDGES, N4);
        fb_layer0<<<NB, LT, 0, stream>>>(
            x, xbf0, ebuf, cursor, node_start, gperm,
            Wl, bl, Wr, Wlin, blin, xbf1);
        fb_layerN<<<NB, LT, 0, stream>>>(
            xbf1, ebuf, cursor, node_start, gperm,
            Wl + D * D, bl + D, Wr + D * D, Wlin + D * D, blin + D,
            nullptr, xbf2, 1);
        fb_layerN<<<NB, LT, 0, stream>>>(
            xbf2, ebuf, cursor, node_start, gperm,
            Wl + 2 * D * D, bl + 2 * D, Wr + 2 * D * D, Wlin + 2 * D * D, blin + 2 * D,
            out, nullptr, 0);
    }
}

// Round 15
// 192.636 us; speedup vs baseline: 6.9401x; 6.9401x over previous
//
#include <hip/hip_runtime.h>

#define N_NODES 100000
#define N_EDGES 3200000
#define D 16

#define TILE 128                           // dst nodes per bucket
#define NB ((N_NODES + TILE - 1) / TILE)   // 782 buckets
#define CAP 4608                           // per-bucket ebuf region (mean 4096, +8 sigma)
#define NBLK 500                           // scatter blocks
#define SEG (N_EDGES / NBLK)               // 6400 edges per scatter block
#define BINT 1024                          // threads for pre kernel
#define CVTB 391                           // cvt blocks: ceil(400000/1024)
#define LT 512                             // threads for layer kernels (= TILE*4)
#define N4 (N_NODES * D / 4)               // 400000 float4 quarters

// ---- bf16 helpers (RNE) ----
__device__ __forceinline__ unsigned packbf(float a, float b) {
    unsigned ua = __float_as_uint(a); ua += 0x7FFFu + ((ua >> 16) & 1u);
    unsigned ub = __float_as_uint(b); ub += 0x7FFFu + ((ub >> 16) & 1u);
    return (ua >> 16) | (ub & 0xFFFF0000u);
}
#define BLO(u) __uint_as_float((u) << 16)
#define BHI(u) __uint_as_float((u) & 0xFFFF0000u)

// ---- fused pre-pass: blocks [0,NBLK) bucket-scatter edges; rest convert x->bf16 ----
// packed entry: (dst & 127) << 17 | src   (src < 2^17)
__global__ __launch_bounds__(BINT, 8) void pre_kernel(
        const float* __restrict__ x, unsigned* __restrict__ xbf,
        const int* __restrict__ src, const int* __restrict__ dst,
        int* __restrict__ cursor, unsigned* __restrict__ ebuf) {
    __shared__ int lcnt[NB];
    __shared__ int ldiff[NB];
    __shared__ unsigned sorted[SEG];
    __shared__ unsigned short sbkt[SEG];
    __shared__ int wsum[16];
    int tid = threadIdx.x;

    if (blockIdx.x >= NBLK) {              // ---- cvt path ----
        int t = (blockIdx.x - NBLK) * BINT + tid;
        if (t < N4) {
            float4 v = *(const float4*)(x + (size_t)t * 4);
            uint2 o; o.x = packbf(v.x, v.y); o.y = packbf(v.z, v.w);
            *(uint2*)(xbf + (size_t)t * 2) = o;
        }
        return;
    }

    // ---- scatter path ----
    for (int i = tid; i < NB; i += BINT) lcnt[i] = 0;
    __syncthreads();
    int b0 = blockIdx.x * SEG;
    for (int e = b0 + tid * 4; e < b0 + SEG; e += BINT * 4) {
        int4 d4 = *(const int4*)(dst + e);
        atomicAdd(&lcnt[d4.x >> 7], 1);
        atomicAdd(&lcnt[d4.y >> 7], 1);
        atomicAdd(&lcnt[d4.z >> 7], 1);
        atomicAdd(&lcnt[d4.w >> 7], 1);
    }
    __syncthreads();
    // wave-shfl scan over NB counters (1/thread), reserve global space
    {
        int lane = tid & 63, wv = tid >> 6;
        int v = (tid < NB) ? lcnt[tid] : 0;
        int s = v;
        #pragma unroll
        for (int d_ = 1; d_ < 64; d_ <<= 1) {
            int u = __shfl_up(s, d_, 64);
            if (lane >= d_) s += u;
        }
        if (lane == 63) wsum[wv] = s;
        __syncthreads();
        if (tid == 0) {
            int a = 0;
            #pragma unroll
            for (int i = 0; i < 16; i++) { int t_ = wsum[i]; wsum[i] = a; a += t_; }
        }
        __syncthreads();
        int excl = wsum[wv] + s - v;
        if (tid < NB) {
            int g = v ? (tid * CAP + atomicAdd(&cursor[tid], v)) : 0;
            ldiff[tid] = g - excl;
            lcnt[tid] = excl;              // running local cursor
        }
        __syncthreads();
    }
    // re-read edges (L2-warm), place into bucket-sorted LDS
    for (int e = b0 + tid * 4; e < b0 + SEG; e += BINT * 4) {
        int4 d4 = *(const int4*)(dst + e);
        int4 s4 = *(const int4*)(src + e);
        int b_, pos;
        b_ = d4.x >> 7; pos = atomicAdd(&lcnt[b_], 1);
        sorted[pos] = ((unsigned)(d4.x & 127) << 17) | (unsigned)s4.x; sbkt[pos] = (unsigned short)b_;
        b_ = d4.y >> 7; pos = atomicAdd(&lcnt[b_], 1);
        sorted[pos] = ((unsigned)(d4.y & 127) << 17) | (unsigned)s4.y; sbkt[pos] = (unsigned short)b_;
        b_ = d4.z >> 7; pos = atomicAdd(&lcnt[b_], 1);
        sorted[pos] = ((unsigned)(d4.z & 127) << 17) | (unsigned)s4.z; sbkt[pos] = (unsigned short)b_;
        b_ = d4.w >> 7; pos = atomicAdd(&lcnt[b_], 1);
        sorted[pos] = ((unsigned)(d4.w & 127) << 17) | (unsigned)s4.w; sbkt[pos] = (unsigned short)b_;
    }
    __syncthreads();
    // coalesced write-out
    for (int i = tid; i < SEG; i += BINT) {
        int b_ = sbkt[i];
        ebuf[ldiff[b_] + i] = sorted[i];
    }
}

// ---- shared aggregation + transform body ----
// 4-lane group per node; 2 lanes/edge, 16B bf16 gathers, SOFTWARE-PIPELINED
// (batch i+1's loads issue before batch i's sums consume). Shuffles move the
// half-row sums into the quarter layout the 16x16 transform uses.
#define LDG(j) (*(const uint4*)(xbf + (size_t)(se2[(j) + lane2] & 0x1FFFF) * 8 + ho))
#define ACC8(g) do { \
    acc[0] += BLO((g).x); acc[1] += BHI((g).x); acc[2] += BLO((g).y); acc[3] += BHI((g).y); \
    acc[4] += BLO((g).z); acc[5] += BHI((g).z); acc[6] += BLO((g).w); acc[7] += BHI((g).w); } while (0)

__device__ __forceinline__ void agg_xform(
    const float* __restrict__ xin, const unsigned* __restrict__ xbf,
    const unsigned* se2, const int* lofs, int n_loc,
    const float* sWl, const float* sWc, const float* sbc,
    float* __restrict__ xout, unsigned* __restrict__ xbf_out,
    int emit_bf, int b, int N, int tid) {
    int q = tid & 3;
    int n = b * TILE + n_loc;
    if (n >= N) return;

    float4 xq = *(const float4*)(xin + (size_t)n * D + q * 4);  // self row (fp32, issued early)
    float xv[4] = { xq.x, xq.y, xq.z, xq.w };

    int s0 = lofs[n_loc];
    int s1 = lofs[n_loc + 1];
    int deg = s1 - s0;
    int lane2 = q >> 1;          // edge parity this lane covers
    int ho = (q & 1) * 4;        // uint offset of row half (16B)

    float acc[8] = {0.f,0.f,0.f,0.f,0.f,0.f,0.f,0.f};
    int end8 = s0 + (deg & ~7);
    int i = s0;
    if (i < end8) {
        uint4 c0 = LDG(i + 0), c1 = LDG(i + 2), c2 = LDG(i + 4), c3 = LDG(i + 6);
        i += 8;
        for (; i < end8; i += 8) {
            uint4 n0 = LDG(i + 0), n1 = LDG(i + 2), n2 = LDG(i + 4), n3 = LDG(i + 6);
            ACC8(c0); ACC8(c1); ACC8(c2); ACC8(c3);
            c0 = n0; c1 = n1; c2 = n2; c3 = n3;
        }
        ACC8(c0); ACC8(c1); ACC8(c2); ACC8(c3);
    }
    for (; i + 2 <= s1; i += 2) {
        uint4 g = LDG(i);
        ACC8(g);
    }
    if (i < s1 && lane2 == 0) {              // odd leftover edge: lanes q=0,1 only
        uint4 g = *(const uint4*)(xbf + (size_t)(se2[i] & 0x1FFFF) * 8 + ho);
        ACC8(g);
    }
    #pragma unroll
    for (int k = 0; k < 8; k++) acc[k] += __shfl_xor(acc[k], 2, 4);  // combine parities

    // redistribute half-row sums -> quarter layout: lane q wants f[4q+k]
    int srcAbs = (tid & 63 & ~3) | (q >> 1);
    float inv = 1.0f / fmaxf((float)deg, 1.0f);
    float a[4];
    #pragma unroll
    for (int k = 0; k < 4; k++) {
        float lo = __shfl(acc[k], srcAbs);
        float hi = __shfl(acc[4 + k], srcAbs);
        a[k] = ((q & 1) ? hi : lo) * inv;
    }

    float o[4];
    #pragma unroll
    for (int j = 0; j < D; j++) {
        float p = 0.f;
        #pragma unroll
        for (int k = 0; k < 4; k++) {
            int kk = q * 4 + k;
            p += a[k] * sWl[j * D + kk] + xv[k] * sWc[j * D + kk];
        }
        p += __shfl_xor(p, 1, 4);
        p += __shfl_xor(p, 2, 4);
        if ((j >> 2) == q) o[j & 3] = p + sbc[j];
    }
    *(float4*)(xout + (size_t)n * D + q * 4) = make_float4(o[0], o[1], o[2], o[3]);
    if (emit_bf) {
        uint2 ob; ob.x = packbf(o[0], o[1]); ob.y = packbf(o[2], o[3]);
        *(uint2*)(xbf_out + (size_t)n * 8 + q * 2) = ob;
    }
}

// ---- layer 1: LDS counting sort + degree rank + agg/transform ----
__global__ void layer0_kernel(
        const float* __restrict__ xin, const unsigned* __restrict__ xbf,
        unsigned* __restrict__ ebuf, const int* __restrict__ cnt,
        int* __restrict__ node_start, int* __restrict__ gperm,
        const float* __restrict__ Wl, const float* __restrict__ bl,
        const float* __restrict__ Wr, const float* __restrict__ Wlin,
        const float* __restrict__ blin,
        float* __restrict__ xout, unsigned* __restrict__ xbf_out, int N) {
    __shared__ unsigned se[CAP];
    __shared__ unsigned se2[CAP];
    __shared__ int lcnt[TILE];
    __shared__ int lofs[TILE + 1];
    __shared__ int sdeg[TILE];
    __shared__ int perm[TILE];
    __shared__ float sWl[D * D];
    __shared__ float sWc[D * D];
    __shared__ float sbc[D];

    int tid = threadIdx.x;
    int b = blockIdx.x;
    int base = b * CAP;
    int nE = min(cnt[b], CAP);
    int nE4 = (nE + 3) >> 2;

    if (tid < D * D) { sWl[tid] = Wl[tid]; sWc[tid] = Wr[tid] + Wlin[tid]; }
    if (tid < D) sbc[tid] = bl[tid] + blin[tid];
    if (tid < TILE) lcnt[tid] = 0;
    // uint4 staging of bucket edges
    for (int i = tid; i < nE4; i += LT)
        ((uint4*)se)[i] = ((const uint4*)(ebuf + base))[i];
    __syncthreads();
    for (int i = tid; i < nE; i += LT)
        atomicAdd(&lcnt[se[i] >> 17], 1);
    __syncthreads();
    // single-wave shfl scan over TILE counters (2/lane)
    if (tid < 64) {
        int l2 = tid * 2;
        int c0 = lcnt[l2], c1 = lcnt[l2 + 1];
        int v = c0 + c1, s = v;
        #pragma unroll
        for (int d_ = 1; d_ < 64; d_ <<= 1) {
            int u = __shfl_up(s, d_, 64);
            if (tid >= d_) s += u;
        }
        int excl = s - v;
        lofs[l2] = excl; sdeg[l2] = c0; lcnt[l2] = excl;
        node_start[b * TILE + l2] = excl;
        int e1 = excl + c0;
        lofs[l2 + 1] = e1; sdeg[l2 + 1] = c1; lcnt[l2 + 1] = e1;
        node_start[b * TILE + l2 + 1] = e1;
        if (tid == 63) lofs[TILE] = s;       // == nE
    }
    __syncthreads();
    // degree rank (desc)
    if (tid < TILE) {
        int dm = sdeg[tid];
        int r = 0;
        for (int j = 0; j < TILE; j++) {
            int dj = sdeg[j];
            r += (dj > dm) || (dj == dm && j < tid);
        }
        perm[r] = tid;
        gperm[b * TILE + r] = tid;
    }
    // reorder into sorted se2
    for (int i = tid; i < nE; i += LT) {
        unsigned p = se[i];
        int pos = atomicAdd(&lcnt[p >> 17], 1);
        se2[pos] = p;
    }
    __syncthreads();
    for (int i = tid; i < nE4; i += LT)      // uint4 sorted write-back
        ((uint4*)(ebuf + base))[i] = ((const uint4*)se2)[i];

    agg_xform(xin, xbf, se2, lofs, perm[tid >> 2], sWl, sWc, sbc,
              xout, xbf_out, 1, b, N, tid);
}

// ---- layers 2/3: stage sorted edges, agg/transform ----
__global__ __launch_bounds__(LT, 8) void layerN_kernel(
        const float* __restrict__ xin, const unsigned* __restrict__ xbf,
        const unsigned* __restrict__ ebuf, const int* __restrict__ cnt,
        const int* __restrict__ node_start, const int* __restrict__ gperm,
        const float* __restrict__ Wl, const float* __restrict__ bl,
        const float* __restrict__ Wr, const float* __restrict__ Wlin,
        const float* __restrict__ blin,
        float* __restrict__ xout, unsigned* __restrict__ xbf_out,
        int emit_bf, int N) {
    __shared__ unsigned se2[CAP];
    __shared__ int lofs[TILE + 1];
    __shared__ float sWl[D * D];
    __shared__ float sWc[D * D];
    __shared__ float sbc[D];

    int tid = threadIdx.x;
    int b = blockIdx.x;
    int base = b * CAP;
    int nE = min(cnt[b], CAP);
    int nE4 = (nE + 3) >> 2;

    if (tid < D * D) { sWl[tid] = Wl[tid]; sWc[tid] = Wr[tid] + Wlin[tid]; }
    if (tid < D) sbc[tid] = bl[tid] + blin[tid];
    if (tid < TILE) lofs[tid] = node_start[b * TILE + tid];
    if (tid == 0) lofs[TILE] = nE;
    for (int i = tid; i < nE4; i += LT)      // uint4 staging
        ((uint4*)se2)[i] = ((const uint4*)(ebuf + base))[i];
    int n_loc = gperm[b * TILE + (tid >> 2)];
    __syncthreads();

    agg_xform(xin, xbf, se2, lofs, n_loc, sWl, sWc, sbc,
              xout, xbf_out, emit_bf, b, N, tid);
}

extern "C" void kernel_launch(void* const* d_in, const int* in_sizes, int n_in,
                              void* d_out, int out_size, void* d_ws, size_t ws_size,
                              hipStream_t stream) {
    const float* x    = (const float*)d_in[0];
    const int*   ei   = (const int*)d_in[1];   // (2, E): first E = src, next E = dst
    const float* Wl   = (const float*)d_in[2];
    const float* bl   = (const float*)d_in[3];
    const float* Wr   = (const float*)d_in[4];
    const float* Wlin = (const float*)d_in[5];
    const float* blin = (const float*)d_in[6];
    float* out = (float*)d_out;

    const int* src = ei;
    const int* dst = ei + N_EDGES;

    char* w = (char*)d_ws;
    unsigned* ebuf   = (unsigned*)w;  w += (size_t)NB * CAP * 4;        // 14.4 MB
    float* bufA      = (float*)w;     w += (size_t)N_NODES * D * 4;     // 6.4 MB
    float* bufB      = (float*)w;     w += (size_t)N_NODES * D * 4;     // 6.4 MB
    unsigned* xbf0   = (unsigned*)w;  w += (size_t)N_NODES * 8 * 4;     // 3.2 MB
    unsigned* xbf1   = (unsigned*)w;  w += (size_t)N_NODES * 8 * 4;     // 3.2 MB
    int*   cursor    = (int*)w;       w += (size_t)NB * 4;
    int*   node_start= (int*)w;       w += (size_t)NB * TILE * 4;       // 400 KB
    int*   gperm     = (int*)w;       w += (size_t)NB * TILE * 4;       // 400 KB

    hipMemsetAsync(cursor, 0, (size_t)NB * 4, stream);
    pre_kernel<<<NBLK + CVTB, BINT, 0, stream>>>(x, xbf0, src, dst, cursor, ebuf);

    layer0_kernel<<<NB, LT, 0, stream>>>(
        x, xbf0, ebuf, cursor, node_start, gperm,
        Wl, bl, Wr, Wlin, blin, bufA, xbf1, N_NODES);
    layerN_kernel<<<NB, LT, 0, stream>>>(
        bufA, xbf1, ebuf, cursor, node_start, gperm,
        Wl + D * D, bl + D, Wr + D * D, Wlin + D * D, blin + D, bufB, xbf0, 1, N_NODES);
    layerN_kernel<<<NB, LT, 0, stream>>>(
        bufB, xbf0, ebuf, cursor, node_start, gperm,
        Wl + 2 * D * D, bl + 2 * D, Wr + 2 * D * D, Wlin + 2 * D * D, blin + 2 * D,
        out, nullptr, 0, N_NODES);
}